// Round 9
// baseline (126.636 us; speedup 1.0000x reference)
//
#include <hip/hip_runtime.h>
#include <hip/hip_bf16.h>
#include <cstdint>
#include <cstddef>

#define B_  2
#define T_  2048
#define D_  1024
#define H_  16
#define M_  (B_*T_)   // 4096 rows total

typedef __bf16 bf16_t;
typedef __attribute__((ext_vector_type(8))) __bf16 bf16x8;
typedef __attribute__((ext_vector_type(4))) __bf16 bf16x4;
typedef __attribute__((ext_vector_type(4))) float f32x4;
typedef __attribute__((ext_vector_type(16))) float f32x16;
typedef unsigned int u32;
typedef __attribute__((ext_vector_type(4))) u32 u32x4;

#define MFMA16(a,b,c) __builtin_amdgcn_mfma_f32_16x16x32_bf16(a,b,c,0,0,0)
#define MFMA32(a,b,c) __builtin_amdgcn_mfma_f32_32x32x16_bf16(a,b,c,0,0,0)
#define EXP2(x) __builtin_amdgcn_exp2f(x)

// 0.125 * log2(e): folds 1/sqrt(DH) and the e->2 base change into Wq
#define QSCALE 0.18033688011112042f
// defer-max threshold in log2 domain: skip O-rescale while P <= 2^10
#define DEFER_THR 10.0f

__device__ inline void async16(const void* g, void* l) {
  __builtin_amdgcn_global_load_lds((const __attribute__((address_space(1))) void*)g,
                                   (__attribute__((address_space(3))) void*)l, 16, 0, 0);
}

__device__ __forceinline__ f32x16 zero16() {
  f32x16 z;
  #pragma unroll
  for (int i = 0; i < 16; ++i) z[i] = 0.f;
  return z;
}

// pack two f32 -> one u32 of 2 bf16 (compiler fuses to v_cvt_pk_bf16_f32)
__device__ __forceinline__ u32 pk2(float lo, float hi) {
  u32 a = __builtin_bit_cast(unsigned short, (__bf16)lo);
  u32 b = __builtin_bit_cast(unsigned short, (__bf16)hi);
  return a | (b << 16);
}
// lane^32 exchange via shfl (ds_bpermute) — semantics proven good (r4/r5).
// NOTE: __builtin_amdgcn_permlane32_swap(u,u) is NOT usable: r3/r6 failures.
__device__ __forceinline__ float xswap_max(float x) {
  return fmaxf(x, __shfl_xor(x, 32));
}
__device__ __forceinline__ float xswap_sum(float x) {
  return x + __shfl_xor(x, 32);
}

// ---------------- cast kernels ----------------
__global__ __launch_bounds__(256) void cast_x_k(const float* __restrict__ in,
                                                bf16_t* __restrict__ out, int n8) {
  int i = blockIdx.x * 256 + threadIdx.x;
  if (i >= n8) return;
  const float4* p = (const float4*)in + 2 * (size_t)i;
  float4 a = p[0], b = p[1];
  bf16x8 r = { (__bf16)a.x, (__bf16)a.y, (__bf16)a.z, (__bf16)a.w,
               (__bf16)b.x, (__bf16)b.y, (__bf16)b.z, (__bf16)b.w };
  *((bf16x8*)out + i) = r;
}

__global__ __launch_bounds__(256) void cast_w_k(const float* __restrict__ wq,
                                                const float* __restrict__ wk,
                                                const float* __restrict__ wv,
                                                const float* __restrict__ wo,
                                                bf16_t* __restrict__ outbase) {
  const float* src = blockIdx.y == 0 ? wq : blockIdx.y == 1 ? wk : blockIdx.y == 2 ? wv : wo;
  const float sc = (blockIdx.y == 0) ? QSCALE : 1.0f;
  bf16_t* out = outbase + (size_t)blockIdx.y * D_ * D_;
  int i = blockIdx.x * 256 + threadIdx.x;
  const float4* p = (const float4*)src + 2 * (size_t)i;
  float4 a = p[0], b = p[1];
  bf16x8 r = { (__bf16)(a.x*sc), (__bf16)(a.y*sc), (__bf16)(a.z*sc), (__bf16)(a.w*sc),
               (__bf16)(b.x*sc), (__bf16)(b.y*sc), (__bf16)(b.z*sc), (__bf16)(b.w*sc) };
  *((bf16x8*)out + i) = r;
}

// ---------------- 128x128 NT GEMM core (C = A * W^T) ----------------
template<typename OUT>
__device__ __forceinline__ void gemm_bt_128(const bf16_t* __restrict__ A,
                                            const bf16_t* __restrict__ W,
                                            OUT* __restrict__ C,
                                            int Kdim, int ldc_n, int brow, int bcol) {
  __shared__ __align__(16) bf16_t As[128 * 32];
  __shared__ __align__(16) bf16_t Bs[128 * 32];
  const int lane = threadIdx.x & 63;
  const int w    = threadIdx.x >> 6;
  const int lo   = lane & 15, hi = lane >> 4;
  const int wr   = w >> 1, wc = w & 1;

  f32x4 acc[4][4];
  #pragma unroll
  for (int i = 0; i < 4; ++i)
    #pragma unroll
    for (int j = 0; j < 4; ++j) acc[i][j] = (f32x4){0.f, 0.f, 0.f, 0.f};

  for (int kt = 0; kt < Kdim; kt += 32) {
    #pragma unroll
    for (int i = 0; i < 2; ++i) {
      int chunk = w * 2 + i;
      int r = chunk * 16 + (lane >> 2);
      int c = (lane & 3) * 8;
      async16(A + (size_t)(brow + r) * Kdim + kt + c, (char*)As + chunk * 1024);
      async16(W + (size_t)(bcol + r) * Kdim + kt + c, (char*)Bs + chunk * 1024);
    }
    __syncthreads();
    bf16x8 af[4], bfr[4];
    #pragma unroll
    for (int mi = 0; mi < 4; ++mi)
      af[mi] = *(const bf16x8*)&As[(wr * 64 + mi * 16 + lo) * 32 + hi * 8];
    #pragma unroll
    for (int ni = 0; ni < 4; ++ni)
      bfr[ni] = *(const bf16x8*)&Bs[(wc * 64 + ni * 16 + lo) * 32 + hi * 8];
    #pragma unroll
    for (int mi = 0; mi < 4; ++mi)
      #pragma unroll
      for (int ni = 0; ni < 4; ++ni)
        acc[mi][ni] = MFMA16(af[mi], bfr[ni], acc[mi][ni]);
    __syncthreads();
  }

  #pragma unroll
  for (int mi = 0; mi < 4; ++mi)
    #pragma unroll
    for (int ni = 0; ni < 4; ++ni)
      #pragma unroll
      for (int i = 0; i < 4; ++i) {
        int row = brow + wr * 64 + mi * 16 + hi * 4 + i;
        int col = bcol + wc * 64 + ni * 16 + lo;
        C[(size_t)row * ldc_n + col] = (OUT)acc[mi][ni][i];
      }
}

__global__ __launch_bounds__(256) void qkv_gemm_k(const bf16_t* __restrict__ xb,
                                                  const bf16_t* __restrict__ wqb,
                                                  const bf16_t* __restrict__ wkb,
                                                  const bf16_t* __restrict__ wvb,
                                                  bf16_t* __restrict__ Q,
                                                  bf16_t* __restrict__ K,
                                                  bf16_t* __restrict__ V) {
  const bf16_t* W = blockIdx.z == 0 ? wqb : blockIdx.z == 1 ? wkb : wvb;
  bf16_t* C       = blockIdx.z == 0 ? Q   : blockIdx.z == 1 ? K   : V;
  gemm_bt_128<bf16_t>(xb, W, C, D_, D_, blockIdx.y * 128, blockIdx.x * 128);
}

__global__ __launch_bounds__(256) void out_gemm_k(const bf16_t* __restrict__ O,
                                                  const bf16_t* __restrict__ wob,
                                                  float* __restrict__ Y) {
  gemm_bt_128<float>(O, wob, Y, D_, D_, blockIdx.y * 128, blockIdx.x * 128);
}

// ---------------- V transpose: V(B,T,D) -> Vt[(b*H+h)*64+dh][T] ----------------
__global__ __launch_bounds__(256) void vt_k(const bf16_t* __restrict__ V,
                                            bf16_t* __restrict__ Vt) {
  __shared__ bf16_t Tl[64][68];
  const int t0 = blockIdx.x * 64;
  const int bh = blockIdx.y, b = bh >> 4, h = bh & 15;
  const int tid = threadIdx.x;
  #pragma unroll
  for (int it = 0; it < 2; ++it) {
    int idx = it * 256 + tid;
    int r = idx >> 3, c8 = (idx & 7) * 8;
    *(bf16x8*)&Tl[r][c8] = *(const bf16x8*)&V[((size_t)(b * T_ + t0 + r)) * D_ + h * 64 + c8];
  }
  __syncthreads();
  #pragma unroll
  for (int it = 0; it < 2; ++it) {
    int idx = it * 256 + tid;
    int dh = idx >> 3, tc = (idx & 7) * 8;
    bf16x8 v;
    #pragma unroll
    for (int j = 0; j < 8; ++j) v[j] = Tl[tc + j][dh];
    *(bf16x8*)&Vt[((size_t)bh * 64 + dh) * T_ + t0 + tc] = v;
  }
}

// ---------------- flash attention: 8 waves, KV-split x2, tau-permuted ----------------
// Block = 512 threads, ONE q-tile (128 rows). Waves 0-3 (group A): KV tiles
// [0, qt]; waves 4-7 (group B): [qt+1, 2qt+1]. Partials merged through LDS.
// tau-trick: QK^T A-rows permuted (quads 1<->2 per 16) so each lane's PV
// B-fragment is its own registers in order -> zero cross-lane ops in PACK_PV.
// Grid (B*H, 16): id%8 = bh%8 keeps a head on one XCD; qt permutation makes
// co-resident block pairs (y, y+8) sum to 17 iterations on every CU.
__global__ __launch_bounds__(512) void attn_k(const bf16_t* __restrict__ Q,
                                              const bf16_t* __restrict__ K,
                                              const bf16_t* __restrict__ Vt,
                                              bf16_t* __restrict__ O) {
  const int bh = blockIdx.x, b = bh >> 4, h = bh & 15;
  const int yy = (int)blockIdx.y;
  const int qt = (yy < 8) ? (15 - 2 * yy) : (2 * (yy - 8));
  const int tid = threadIdx.x;

  __shared__ __align__(16) char smem[65536];

  const bf16_t* Kt0 = K + ((size_t)b * T_) * D_ + h * 64;
  const bf16_t* Vt0 = Vt + (size_t)bh * 64 * T_;

  const int lane = tid & 63, w = tid >> 6;
  const int wl = w & 3, wg = w >> 2;
  const int ln = lane & 31, hi = lane >> 5;
  const int tl = tid & 255;
  // tau: swap quads 1<->2 within each 16 (involution)
  const int tau = (ln & ~12) | (((ln & 4) << 1) | ((ln & 8) >> 1));
  char* sgbase = smem + ((tid >= 256) ? 32768 : 0);  // staging base (thread's group)
  char* cgbase = smem + wg * 32768;                  // compute base (wave's group)
  float* mo = (float*)smem;                          // merge: [4][64][33] f32
  float* ml = (float*)(smem + 33792);                // merge: [4][64][2]  f32

  const int q_abs = qt * 128 + wl * 32 + ln;
  bf16x8 qf[4];
  {
    const bf16_t* Qrow = Q + ((size_t)b * T_ + q_abs) * D_ + h * 64;
    #pragma unroll
    for (int ks = 0; ks < 4; ++ks)
      qf[ks] = *(const bf16x8*)(Qrow + ks * 16 + hi * 8);
  }

  f32x16 o0 = zero16(), o1 = zero16();   // O^T: rows=dh (0..31 / 32..63), col=q=ln
  float m = -1e30f, l = 0.f;

  const int jc    = qt + 1;              // iterations per group
  const int jd    = 2 * qt + (wl >> 1);  // my diagonal KV tile
  const int tbase = wg ? (qt + 1) : 0;   // group KV range start

#define STAGE8(BUF, TT)                                                       \
  {                                                                           \
    char* kd = sgbase + (BUF) * 8192;                                         \
    char* vd = sgbase + 16384 + (BUF) * 8192;                                 \
    _Pragma("unroll")                                                         \
    for (int it = 0; it < 2; ++it) {                                          \
      int c = it * 256 + tl;                                                  \
      int row = c >> 3, sl = c & 7;                                           \
      int slg = sl ^ (row & 7);                                               \
      async16(Kt0 + ((size_t)((TT) * 64 + row)) * D_ + slg * 8, kd + c * 16); \
      async16(Vt0 + (size_t)row * T_ + (TT) * 64 + slg * 8, vd + c * 16);     \
    }                                                                         \
  }

  // P regs are already in fragment order (tau-trick): 4 pk2, no shuffles.
#define PACK_PV8(PS, KS, VB)                                                  \
  {                                                                           \
    const int r0 = ((KS) & 1) * 8;                                            \
    u32x4 pw = {pk2((PS)[r0 + 0], (PS)[r0 + 1]),                              \
                pk2((PS)[r0 + 2], (PS)[r0 + 3]),                              \
                pk2((PS)[r0 + 4], (PS)[r0 + 5]),                              \
                pk2((PS)[r0 + 6], (PS)[r0 + 7])};                             \
    bf16x8 pb = __builtin_bit_cast(bf16x8, pw);                               \
    const int sg = (KS) * 2 + hi;                                             \
    int row = ln;                                                             \
    bf16x8 vf0 = *(const bf16x8*)((VB) + row * 64 + ((sg ^ (row & 7)) * 8));  \
    o0 = MFMA32(vf0, pb, o0);                                                 \
    row = 32 + ln;                                                            \
    bf16x8 vf1 = *(const bf16x8*)((VB) + row * 64 + ((sg ^ (row & 7)) * 8));  \
    o1 = MFMA32(vf1, pb, o1);                                                 \
  }

  STAGE8(0, tbase)
  int cur = 0;
  for (int j = 0; j < jc; ++j) {
    if (j + 1 < jc) {
      STAGE8(cur ^ 1, tbase + j + 1)
      asm volatile("s_waitcnt vmcnt(4)" ::: "memory");
    } else {
      asm volatile("s_waitcnt vmcnt(0)" ::: "memory");
    }
    __builtin_amdgcn_s_barrier();

    const int tt = tbase + j;
    if (tt <= jd) {
      const bf16_t* Kb = (const bf16_t*)(cgbase + cur * 8192);
      const bf16_t* Vb = (const bf16_t*)(cgbase + 16384 + cur * 8192);
      // S^T = K . Q^T with tau-permuted A rows: reg r holds P at
      // kv = (r&7) + 16*(r>>3) + 8*hi  (+32 for s1)
      f32x16 s0 = zero16(), s1 = zero16();
      __builtin_amdgcn_s_setprio(1);
      #pragma unroll
      for (int ks = 0; ks < 4; ++ks) {
        const int sg = ks * 2 + hi;
        int row = tau;
        bf16x8 kf0 = *(const bf16x8*)(Kb + row * 64 + ((sg ^ (row & 7)) * 8));
        s0 = MFMA32(kf0, qf[ks], s0);
        row = 32 + tau;
        bf16x8 kf1 = *(const bf16x8*)(Kb + row * 64 + ((sg ^ (row & 7)) * 8));
        s1 = MFMA32(kf1, qf[ks], s1);
      }
      __builtin_amdgcn_s_setprio(0);
      if (tt == jd) {
        const int kv0 = tt * 64;
        #pragma unroll
        for (int r = 0; r < 16; ++r) {
          const int pos = (r & 7) + 16 * (r >> 3) + 8 * hi;
          if (kv0 + pos      > q_abs) s0[r] = -3e38f;
          if (kv0 + 32 + pos > q_abs) s1[r] = -3e38f;
        }
      }
      // online softmax (log2 domain), tree reductions, defer-max
      float t[16];
      #pragma unroll
      for (int r = 0; r < 16; ++r) t[r] = fmaxf(s0[r], s1[r]);
      #pragma unroll
      for (int st = 8; st >= 1; st >>= 1)
        #pragma unroll
        for (int i = 0; i < st; ++i) t[i] = fmaxf(t[i], t[i + st]);
      float pmax = xswap_max(t[0]);
      if (!__all(pmax - m <= DEFER_THR)) {
        float mn   = fmaxf(m, pmax);
        float corr = EXP2(m - mn);
        m = mn;
        l *= corr;
        #pragma unroll
        for (int r = 0; r < 16; ++r) { o0[r] *= corr; o1[r] *= corr; }
      }
      float u[16];
      #pragma unroll
      for (int r = 0; r < 16; ++r) {
        float p0 = EXP2(s0[r] - m); s0[r] = p0;
        float p1 = EXP2(s1[r] - m); s1[r] = p1;
        u[r] = p0 + p1;
      }
      #pragma unroll
      for (int st = 8; st >= 1; st >>= 1)
        #pragma unroll
        for (int i = 0; i < st; ++i) u[i] += u[i + st];
      l += xswap_sum(u[0]);
      __builtin_amdgcn_s_setprio(1);
      PACK_PV8(s0, 0, Vb)
      PACK_PV8(s0, 1, Vb)
      PACK_PV8(s1, 2, Vb)
      PACK_PV8(s1, 3, Vb)
      __builtin_amdgcn_s_setprio(0);
    }
    __builtin_amdgcn_s_barrier();
    cur ^= 1;
  }

  // ---- merge group B partials into group A, then store ----
  if (wg == 1) {
    float* mop = mo + ((size_t)wl * 64 + lane) * 33;
    #pragma unroll
    for (int r = 0; r < 16; ++r) { mop[r] = o0[r]; mop[16 + r] = o1[r]; }
    float* mlp = ml + ((size_t)wl * 64 + lane) * 2;
    mlp[0] = m; mlp[1] = l;
  }
  __syncthreads();
  if (wg == 0) {
    const float* mop = mo + ((size_t)wl * 64 + lane) * 33;
    const float* mlp = ml + ((size_t)wl * 64 + lane) * 2;
    float mB = mlp[0], lB = mlp[1];
    float mS = fmaxf(m, mB);
    float cA = EXP2(m - mS), cB = EXP2(mB - mS);
    float lS = l * cA + lB * cB;
    float rl = 1.0f / lS;
    bf16_t* Orow = O + ((size_t)b * T_ + q_abs) * D_ + h * 64;
    #pragma unroll
    for (int g = 0; g < 4; ++g) {
      const int dh0 = 8 * g + 4 * hi;
      bf16x4 v0, v1;
      #pragma unroll
      for (int jj = 0; jj < 4; ++jj) {
        v0[jj] = (__bf16)((o0[4 * g + jj] * cA + mop[4 * g + jj] * cB) * rl);
        v1[jj] = (__bf16)((o1[4 * g + jj] * cA + mop[16 + 4 * g + jj] * cB) * rl);
      }
      *(bf16x4*)(Orow + dh0)      = v0;
      *(bf16x4*)(Orow + 32 + dh0) = v1;
    }
  }
#undef STAGE8
#undef PACK_PV8
}

// ---------------- launcher ----------------
extern "C" void kernel_launch(void* const* d_in, const int* in_sizes, int n_in,
                              void* d_out, int out_size, void* d_ws, size_t ws_size,
                              hipStream_t stream) {
  const float* x  = (const float*)d_in[0];
  const float* wq = (const float*)d_in[1];
  const float* wk = (const float*)d_in[2];
  const float* wv = (const float*)d_in[3];
  const float* wo = (const float*)d_in[4];
  float* out = (float*)d_out;

  char* ws = (char*)d_ws;
  bf16_t* xb  = (bf16_t*)(ws);                       // 8 MB
  bf16_t* wqb = (bf16_t*)(ws + (size_t)( 8 << 20));  // 2 MB each
  bf16_t* wkb = (bf16_t*)(ws + (size_t)(10 << 20));
  bf16_t* wvb = (bf16_t*)(ws + (size_t)(12 << 20));
  bf16_t* wob = (bf16_t*)(ws + (size_t)(14 << 20));
  bf16_t* Qb  = (bf16_t*)(ws + (size_t)(16 << 20));  // 8 MB
  bf16_t* Kb  = (bf16_t*)(ws + (size_t)(24 << 20));  // 8 MB
  bf16_t* Vb  = (bf16_t*)(ws + (size_t)(32 << 20));  // 8 MB
  bf16_t* Vtb = (bf16_t*)(ws + (size_t)(40 << 20));  // 8 MB
  bf16_t* Ob  = Vb;   // Vb dead after vt_k; attn output reuses its slot

  (void)in_sizes; (void)n_in; (void)out_size; (void)ws_size;

  cast_x_k<<<dim3(M_ * D_ / 8 / 256), 256, 0, stream>>>(x, xb, M_ * D_ / 8);
  cast_w_k<<<dim3(D_ * D_ / 8 / 256, 4), 256, 0, stream>>>(wq, wk, wv, wo, wqb);
  qkv_gemm_k<<<dim3(D_ / 128, M_ / 128, 3), 256, 0, stream>>>(xb, wqb, wkb, wvb, Qb, Kb, Vb);
  vt_k<<<dim3(T_ / 64, B_ * H_), 256, 0, stream>>>(Vb, Vtb);
  attn_k<<<dim3(B_ * H_, T_ / 128), 512, 0, stream>>>(Qb, Kb, Vtb, Ob);
  out_gemm_k<<<dim3(D_ / 128, M_ / 128), 256, 0, stream>>>(Ob, wob, out);
}

// Round 10
// 112.620 us; speedup vs baseline: 1.1245x; 1.1245x over previous
//
#include <hip/hip_runtime.h>
#include <hip/hip_bf16.h>
#include <cstdint>
#include <cstddef>

#define B_  2
#define T_  2048
#define D_  1024
#define H_  16
#define M_  (B_*T_)   // 4096 rows total

typedef __bf16 bf16_t;
typedef __attribute__((ext_vector_type(8))) __bf16 bf16x8;
typedef __attribute__((ext_vector_type(4))) __bf16 bf16x4;
typedef __attribute__((ext_vector_type(4))) float f32x4;
typedef __attribute__((ext_vector_type(16))) float f32x16;
typedef unsigned int u32;
typedef __attribute__((ext_vector_type(4))) u32 u32x4;

#define MFMA16(a,b,c) __builtin_amdgcn_mfma_f32_16x16x32_bf16(a,b,c,0,0,0)
#define MFMA32(a,b,c) __builtin_amdgcn_mfma_f32_32x32x16_bf16(a,b,c,0,0,0)
#define EXP2(x) __builtin_amdgcn_exp2f(x)

// 0.125 * log2(e): folds 1/sqrt(DH) and the e->2 base change into Wq
#define QSCALE 0.18033688011112042f
// defer-max threshold in log2 domain: skip O-rescale while P <= 2^10
#define DEFER_THR 10.0f

__device__ inline void async16(const void* g, void* l) {
  __builtin_amdgcn_global_load_lds((const __attribute__((address_space(1))) void*)g,
                                   (__attribute__((address_space(3))) void*)l, 16, 0, 0);
}

__device__ __forceinline__ f32x16 zero16() {
  f32x16 z;
  #pragma unroll
  for (int i = 0; i < 16; ++i) z[i] = 0.f;
  return z;
}

// pack two f32 -> one u32 of 2 bf16 (compiler fuses to v_cvt_pk_bf16_f32)
__device__ __forceinline__ u32 pk2(float lo, float hi) {
  u32 a = __builtin_bit_cast(unsigned short, (__bf16)lo);
  u32 b = __builtin_bit_cast(unsigned short, (__bf16)hi);
  return a | (b << 16);
}
// lane^32 exchange via shfl (ds_bpermute) — semantics proven good (r4/r5).
// NOTE: __builtin_amdgcn_permlane32_swap(u,u) is NOT usable: r3/r6 failures.
__device__ __forceinline__ float xswap_max(float x) {
  return fmaxf(x, __shfl_xor(x, 32));
}
__device__ __forceinline__ float xswap_sum(float x) {
  return x + __shfl_xor(x, 32);
}

// ---------------- cast kernels ----------------
__global__ __launch_bounds__(256) void cast_x_k(const float* __restrict__ in,
                                                bf16_t* __restrict__ out, int n8) {
  int i = blockIdx.x * 256 + threadIdx.x;
  if (i >= n8) return;
  const float4* p = (const float4*)in + 2 * (size_t)i;
  float4 a = p[0], b = p[1];
  bf16x8 r = { (__bf16)a.x, (__bf16)a.y, (__bf16)a.z, (__bf16)a.w,
               (__bf16)b.x, (__bf16)b.y, (__bf16)b.z, (__bf16)b.w };
  *((bf16x8*)out + i) = r;
}

__global__ __launch_bounds__(256) void cast_w_k(const float* __restrict__ wq,
                                                const float* __restrict__ wk,
                                                const float* __restrict__ wv,
                                                const float* __restrict__ wo,
                                                bf16_t* __restrict__ outbase) {
  const float* src = blockIdx.y == 0 ? wq : blockIdx.y == 1 ? wk : blockIdx.y == 2 ? wv : wo;
  const float sc = (blockIdx.y == 0) ? QSCALE : 1.0f;
  bf16_t* out = outbase + (size_t)blockIdx.y * D_ * D_;
  int i = blockIdx.x * 256 + threadIdx.x;
  const float4* p = (const float4*)src + 2 * (size_t)i;
  float4 a = p[0], b = p[1];
  bf16x8 r = { (__bf16)(a.x*sc), (__bf16)(a.y*sc), (__bf16)(a.z*sc), (__bf16)(a.w*sc),
               (__bf16)(b.x*sc), (__bf16)(b.y*sc), (__bf16)(b.z*sc), (__bf16)(b.w*sc) };
  *((bf16x8*)out + i) = r;
}

// ---------------- 128x128 NT GEMM core (C = A * W^T) ----------------
template<typename OUT>
__device__ __forceinline__ void gemm_bt_128(const bf16_t* __restrict__ A,
                                            const bf16_t* __restrict__ W,
                                            OUT* __restrict__ C,
                                            int Kdim, int ldc_n, int brow, int bcol) {
  __shared__ __align__(16) bf16_t As[128 * 32];
  __shared__ __align__(16) bf16_t Bs[128 * 32];
  const int lane = threadIdx.x & 63;
  const int w    = threadIdx.x >> 6;
  const int lo   = lane & 15, hi = lane >> 4;
  const int wr   = w >> 1, wc = w & 1;

  f32x4 acc[4][4];
  #pragma unroll
  for (int i = 0; i < 4; ++i)
    #pragma unroll
    for (int j = 0; j < 4; ++j) acc[i][j] = (f32x4){0.f, 0.f, 0.f, 0.f};

  for (int kt = 0; kt < Kdim; kt += 32) {
    #pragma unroll
    for (int i = 0; i < 2; ++i) {
      int chunk = w * 2 + i;
      int r = chunk * 16 + (lane >> 2);
      int c = (lane & 3) * 8;
      async16(A + (size_t)(brow + r) * Kdim + kt + c, (char*)As + chunk * 1024);
      async16(W + (size_t)(bcol + r) * Kdim + kt + c, (char*)Bs + chunk * 1024);
    }
    __syncthreads();
    bf16x8 af[4], bfr[4];
    #pragma unroll
    for (int mi = 0; mi < 4; ++mi)
      af[mi] = *(const bf16x8*)&As[(wr * 64 + mi * 16 + lo) * 32 + hi * 8];
    #pragma unroll
    for (int ni = 0; ni < 4; ++ni)
      bfr[ni] = *(const bf16x8*)&Bs[(wc * 64 + ni * 16 + lo) * 32 + hi * 8];
    #pragma unroll
    for (int mi = 0; mi < 4; ++mi)
      #pragma unroll
      for (int ni = 0; ni < 4; ++ni)
        acc[mi][ni] = MFMA16(af[mi], bfr[ni], acc[mi][ni]);
    __syncthreads();
  }

  #pragma unroll
  for (int mi = 0; mi < 4; ++mi)
    #pragma unroll
    for (int ni = 0; ni < 4; ++ni)
      #pragma unroll
      for (int i = 0; i < 4; ++i) {
        int row = brow + wr * 64 + mi * 16 + hi * 4 + i;
        int col = bcol + wc * 64 + ni * 16 + lo;
        C[(size_t)row * ldc_n + col] = (OUT)acc[mi][ni][i];
      }
}

__global__ __launch_bounds__(256) void qkv_gemm_k(const bf16_t* __restrict__ xb,
                                                  const bf16_t* __restrict__ wqb,
                                                  const bf16_t* __restrict__ wkb,
                                                  const bf16_t* __restrict__ wvb,
                                                  bf16_t* __restrict__ Q,
                                                  bf16_t* __restrict__ K,
                                                  bf16_t* __restrict__ V) {
  const bf16_t* W = blockIdx.z == 0 ? wqb : blockIdx.z == 1 ? wkb : wvb;
  bf16_t* C       = blockIdx.z == 0 ? Q   : blockIdx.z == 1 ? K   : V;
  gemm_bt_128<bf16_t>(xb, W, C, D_, D_, blockIdx.y * 128, blockIdx.x * 128);
}

__global__ __launch_bounds__(256) void out_gemm_k(const bf16_t* __restrict__ O,
                                                  const bf16_t* __restrict__ wob,
                                                  float* __restrict__ Y) {
  gemm_bt_128<float>(O, wob, Y, D_, D_, blockIdx.y * 128, blockIdx.x * 128);
}

// ---------------- V transpose: V(B,T,D) -> Vt[(b*H+h)*64+dh][T] ----------------
__global__ __launch_bounds__(256) void vt_k(const bf16_t* __restrict__ V,
                                            bf16_t* __restrict__ Vt) {
  __shared__ bf16_t Tl[64][68];
  const int t0 = blockIdx.x * 64;
  const int bh = blockIdx.y, b = bh >> 4, h = bh & 15;
  const int tid = threadIdx.x;
  #pragma unroll
  for (int it = 0; it < 2; ++it) {
    int idx = it * 256 + tid;
    int r = idx >> 3, c8 = (idx & 7) * 8;
    *(bf16x8*)&Tl[r][c8] = *(const bf16x8*)&V[((size_t)(b * T_ + t0 + r)) * D_ + h * 64 + c8];
  }
  __syncthreads();
  #pragma unroll
  for (int it = 0; it < 2; ++it) {
    int idx = it * 256 + tid;
    int dh = idx >> 3, tc = (idx & 7) * 8;
    bf16x8 v;
    #pragma unroll
    for (int j = 0; j < 8; ++j) v[j] = Tl[tc + j][dh];
    *(bf16x8*)&Vt[((size_t)bh * 64 + dh) * T_ + t0 + tc] = v;
  }
}

// ---------------- flash attention: 8 waves, KV-split x2, tau-permuted ----------------
// Block = 512 threads, ONE q-tile (128 rows). Waves 0-3 (group A): KV tiles
// [0, qt]; waves 4-7 (group B): [qt+1, 2qt+1]. Partials merged through LDS.
// tau-trick: QK^T A-rows permuted (quads 1<->2 per 16) so each lane's PV
// B-fragment is its own registers in order -> zero cross-lane ops in PACK_PV.
// Scheduling: co-resident blocks hide each other's latency (paired iters ~2x
// faster than solo). qt map pairs near-EQUAL durations on a CU:
//   round-robin model: pair (y, y+8) -> (15-2y, 14-2y)  [adjacent]
//   fill-first model:  pair (same y) -> equal            [ideal]
// Grid (B*H, 16): id%8 = bh%8 keeps each head on one XCD (L2-resident KV).
__global__ __launch_bounds__(512) void attn_k(const bf16_t* __restrict__ Q,
                                              const bf16_t* __restrict__ K,
                                              const bf16_t* __restrict__ Vt,
                                              bf16_t* __restrict__ O) {
  const int bh = blockIdx.x, b = bh >> 4, h = bh & 15;
  const int yy = (int)blockIdx.y;
  const int qt = (yy < 8) ? (15 - 2 * yy) : (30 - 2 * yy);
  const int tid = threadIdx.x;

  __shared__ __align__(16) char smem[65536];

  const bf16_t* Kt0 = K + ((size_t)b * T_) * D_ + h * 64;
  const bf16_t* Vt0 = Vt + (size_t)bh * 64 * T_;

  const int lane = tid & 63, w = tid >> 6;
  const int wl = w & 3, wg = w >> 2;
  const int ln = lane & 31, hi = lane >> 5;
  const int tl = tid & 255;
  // tau: swap quads 1<->2 within each 16 (involution)
  const int tau = (ln & ~12) | (((ln & 4) << 1) | ((ln & 8) >> 1));
  char* sgbase = smem + ((tid >= 256) ? 32768 : 0);  // staging base (thread's group)
  char* cgbase = smem + wg * 32768;                  // compute base (wave's group)
  float* mo = (float*)smem;                          // merge: [4][64][33] f32
  float* ml = (float*)(smem + 33792);                // merge: [4][64][2]  f32

  const int q_abs = qt * 128 + wl * 32 + ln;
  bf16x8 qf[4];
  {
    const bf16_t* Qrow = Q + ((size_t)b * T_ + q_abs) * D_ + h * 64;
    #pragma unroll
    for (int ks = 0; ks < 4; ++ks)
      qf[ks] = *(const bf16x8*)(Qrow + ks * 16 + hi * 8);
  }

  f32x16 o0 = zero16(), o1 = zero16();   // O^T: rows=dh (0..31 / 32..63), col=q=ln
  float m = -1e30f, l = 0.f;

  const int jc    = qt + 1;              // iterations per group
  const int jd    = 2 * qt + (wl >> 1);  // my diagonal KV tile
  const int tbase = wg ? (qt + 1) : 0;   // group KV range start

#define STAGE8(BUF, TT)                                                       \
  {                                                                           \
    char* kd = sgbase + (BUF) * 8192;                                         \
    char* vd = sgbase + 16384 + (BUF) * 8192;                                 \
    _Pragma("unroll")                                                         \
    for (int it = 0; it < 2; ++it) {                                          \
      int c = it * 256 + tl;                                                  \
      int row = c >> 3, sl = c & 7;                                           \
      int slg = sl ^ (row & 7);                                               \
      async16(Kt0 + ((size_t)((TT) * 64 + row)) * D_ + slg * 8, kd + c * 16); \
      async16(Vt0 + (size_t)row * T_ + (TT) * 64 + slg * 8, vd + c * 16);     \
    }                                                                         \
  }

  // P regs are already in fragment order (tau-trick): 4 pk2, no shuffles.
#define PACK_PV8(PS, KS, VB)                                                  \
  {                                                                           \
    const int r0 = ((KS) & 1) * 8;                                            \
    u32x4 pw = {pk2((PS)[r0 + 0], (PS)[r0 + 1]),                              \
                pk2((PS)[r0 + 2], (PS)[r0 + 3]),                              \
                pk2((PS)[r0 + 4], (PS)[r0 + 5]),                              \
                pk2((PS)[r0 + 6], (PS)[r0 + 7])};                             \
    bf16x8 pb = __builtin_bit_cast(bf16x8, pw);                               \
    const int sg = (KS) * 2 + hi;                                             \
    int row = ln;                                                             \
    bf16x8 vf0 = *(const bf16x8*)((VB) + row * 64 + ((sg ^ (row & 7)) * 8));  \
    o0 = MFMA32(vf0, pb, o0);                                                 \
    row = 32 + ln;                                                            \
    bf16x8 vf1 = *(const bf16x8*)((VB) + row * 64 + ((sg ^ (row & 7)) * 8));  \
    o1 = MFMA32(vf1, pb, o1);                                                 \
  }

  STAGE8(0, tbase)
  int cur = 0;
  for (int j = 0; j < jc; ++j) {
    if (j + 1 < jc) {
      STAGE8(cur ^ 1, tbase + j + 1)
      asm volatile("s_waitcnt vmcnt(4)" ::: "memory");
    } else {
      asm volatile("s_waitcnt vmcnt(0)" ::: "memory");
    }
    __builtin_amdgcn_s_barrier();

    const int tt = tbase + j;
    if (tt <= jd) {
      const bf16_t* Kb = (const bf16_t*)(cgbase + cur * 8192);
      const bf16_t* Vb = (const bf16_t*)(cgbase + 16384 + cur * 8192);
      // S^T = K . Q^T with tau-permuted A rows: reg r holds P at
      // kv = (r&7) + 16*(r>>3) + 8*hi  (+32 for s1)
      f32x16 s0 = zero16(), s1 = zero16();
      __builtin_amdgcn_s_setprio(1);
      #pragma unroll
      for (int ks = 0; ks < 4; ++ks) {
        const int sg = ks * 2 + hi;
        int row = tau;
        bf16x8 kf0 = *(const bf16x8*)(Kb + row * 64 + ((sg ^ (row & 7)) * 8));
        s0 = MFMA32(kf0, qf[ks], s0);
        row = 32 + tau;
        bf16x8 kf1 = *(const bf16x8*)(Kb + row * 64 + ((sg ^ (row & 7)) * 8));
        s1 = MFMA32(kf1, qf[ks], s1);
      }
      __builtin_amdgcn_s_setprio(0);
      if (tt == jd) {
        const int kv0 = tt * 64;
        #pragma unroll
        for (int r = 0; r < 16; ++r) {
          const int pos = (r & 7) + 16 * (r >> 3) + 8 * hi;
          if (kv0 + pos      > q_abs) s0[r] = -3e38f;
          if (kv0 + 32 + pos > q_abs) s1[r] = -3e38f;
        }
      }
      // online softmax (log2 domain), tree reductions, defer-max
      float t[16];
      #pragma unroll
      for (int r = 0; r < 16; ++r) t[r] = fmaxf(s0[r], s1[r]);
      #pragma unroll
      for (int st = 8; st >= 1; st >>= 1)
        #pragma unroll
        for (int i = 0; i < st; ++i) t[i] = fmaxf(t[i], t[i + st]);
      float pmax = xswap_max(t[0]);
      if (!__all(pmax - m <= DEFER_THR)) {
        float mn   = fmaxf(m, pmax);
        float corr = EXP2(m - mn);
        m = mn;
        l *= corr;
        #pragma unroll
        for (int r = 0; r < 16; ++r) { o0[r] *= corr; o1[r] *= corr; }
      }
      float u[16];
      #pragma unroll
      for (int r = 0; r < 16; ++r) {
        float p0 = EXP2(s0[r] - m); s0[r] = p0;
        float p1 = EXP2(s1[r] - m); s1[r] = p1;
        u[r] = p0 + p1;
      }
      #pragma unroll
      for (int st = 8; st >= 1; st >>= 1)
        #pragma unroll
        for (int i = 0; i < st; ++i) u[i] += u[i + st];
      l += xswap_sum(u[0]);
      __builtin_amdgcn_s_setprio(1);
      PACK_PV8(s0, 0, Vb)
      PACK_PV8(s0, 1, Vb)
      PACK_PV8(s1, 2, Vb)
      PACK_PV8(s1, 3, Vb)
      __builtin_amdgcn_s_setprio(0);
    }
    __builtin_amdgcn_s_barrier();
    cur ^= 1;
  }

  // ---- merge group B partials into group A, then store ----
  if (wg == 1) {
    float* mop = mo + ((size_t)wl * 64 + lane) * 33;
    #pragma unroll
    for (int r = 0; r < 16; ++r) { mop[r] = o0[r]; mop[16 + r] = o1[r]; }
    float* mlp = ml + ((size_t)wl * 64 + lane) * 2;
    mlp[0] = m; mlp[1] = l;
  }
  __syncthreads();
  if (wg == 0) {
    const float* mop = mo + ((size_t)wl * 64 + lane) * 33;
    const float* mlp = ml + ((size_t)wl * 64 + lane) * 2;
    float mB = mlp[0], lB = mlp[1];
    float mS = fmaxf(m, mB);
    float cA = EXP2(m - mS), cB = EXP2(mB - mS);
    float lS = l * cA + lB * cB;
    float rl = 1.0f / lS;
    bf16_t* Orow = O + ((size_t)b * T_ + q_abs) * D_ + h * 64;
    #pragma unroll
    for (int g = 0; g < 4; ++g) {
      const int dh0 = 8 * g + 4 * hi;
      bf16x4 v0, v1;
      #pragma unroll
      for (int jj = 0; jj < 4; ++jj) {
        v0[jj] = (__bf16)((o0[4 * g + jj] * cA + mop[4 * g + jj] * cB) * rl);
        v1[jj] = (__bf16)((o1[4 * g + jj] * cA + mop[16 + 4 * g + jj] * cB) * rl);
      }
      *(bf16x4*)(Orow + dh0)      = v0;
      *(bf16x4*)(Orow + 32 + dh0) = v1;
    }
  }
#undef STAGE8
#undef PACK_PV8
}

// ---------------- launcher ----------------
extern "C" void kernel_launch(void* const* d_in, const int* in_sizes, int n_in,
                              void* d_out, int out_size, void* d_ws, size_t ws_size,
                              hipStream_t stream) {
  const float* x  = (const float*)d_in[0];
  const float* wq = (const float*)d_in[1];
  const float* wk = (const float*)d_in[2];
  const float* wv = (const float*)d_in[3];
  const float* wo = (const float*)d_in[4];
  float* out = (float*)d_out;

  char* ws = (char*)d_ws;
  bf16_t* xb  = (bf16_t*)(ws);                       // 8 MB
  bf16_t* wqb = (bf16_t*)(ws + (size_t)( 8 << 20));  // 2 MB each
  bf16_t* wkb = (bf16_t*)(ws + (size_t)(10 << 20));
  bf16_t* wvb = (bf16_t*)(ws + (size_t)(12 << 20));
  bf16_t* wob = (bf16_t*)(ws + (size_t)(14 << 20));
  bf16_t* Qb  = (bf16_t*)(ws + (size_t)(16 << 20));  // 8 MB
  bf16_t* Kb  = (bf16_t*)(ws + (size_t)(24 << 20));  // 8 MB
  bf16_t* Vb  = (bf16_t*)(ws + (size_t)(32 << 20));  // 8 MB
  bf16_t* Vtb = (bf16_t*)(ws + (size_t)(40 << 20));  // 8 MB
  bf16_t* Ob  = Vb;   // Vb dead after vt_k; attn output reuses its slot

  (void)in_sizes; (void)n_in; (void)out_size; (void)ws_size;

  cast_x_k<<<dim3(M_ * D_ / 8 / 256), 256, 0, stream>>>(x, xb, M_ * D_ / 8);
  cast_w_k<<<dim3(D_ * D_ / 8 / 256, 4), 256, 0, stream>>>(wq, wk, wv, wo, wqb);
  qkv_gemm_k<<<dim3(D_ / 128, M_ / 128, 3), 256, 0, stream>>>(xb, wqb, wkb, wvb, Qb, Kb, Vb);
  vt_k<<<dim3(T_ / 64, B_ * H_), 256, 0, stream>>>(Vb, Vtb);
  attn_k<<<dim3(B_ * H_, T_ / 128), 512, 0, stream>>>(Qb, Kb, Vtb, Ob);
  out_gemm_k<<<dim3(D_ / 128, M_ / 128), 256, 0, stream>>>(Ob, wob, out);
}